// Round 7
// baseline (582.860 us; speedup 1.0000x reference)
//
#include <hip/hip_runtime.h>
#include <cstddef>

// Problem constants (reference: B=32, L=128, N=64, D=64, H=4, DH=16)
#define BB   32
#define LL   128
#define NN   64
#define DD   64
#define HH   4

typedef float v2f __attribute__((ext_vector_type(2)));

__device__ __forceinline__ float bcast(float v, int l) {
    return __int_as_float(__builtin_amdgcn_readlane(__float_as_int(v), l));
}
__device__ __forceinline__ float sigmoidf_(float x) {
    return 1.0f / (1.0f + __expf(-x));
}
__device__ __forceinline__ float tanhf_(float x) {
    float e = __expf(2.0f * x);
    return 1.0f - 2.0f / (e + 1.0f);
}

// Anti-rematerialization fence: launder v through an opaque identity so the
// compiler cannot re-derive it from memory inside the recurrence loop. Forces
// the value to be carried in a VGPR for its whole live range (R5/R6 showed
// the allocator otherwise sinks the weight loads into the t-loop: VGPR=144,
// latency-bound at 50% VALUBusy).
__device__ __forceinline__ void pin(v2f& v) {
    asm volatile("" : "+v"(v));
}

// Load the 4 gate rows (i,f,g,o) of hidden unit u for variable n into
// packed register pairs: wif[k] = {Wi[k], Wf[k]}, wgo[k] = {Wg[k], Wo[k]}.
__device__ __forceinline__ void load_gate_rows(const float* __restrict__ W,
                                               int n, int u,
                                               v2f (&wif)[64], v2f (&wgo)[64]) {
    const float4* Ri = reinterpret_cast<const float4*>(W + ((size_t)n * 256 + u      ) * 64);
    const float4* Rf = reinterpret_cast<const float4*>(W + ((size_t)n * 256 + u +  64) * 64);
    const float4* Rg = reinterpret_cast<const float4*>(W + ((size_t)n * 256 + u + 128) * 64);
    const float4* Ro = reinterpret_cast<const float4*>(W + ((size_t)n * 256 + u + 192) * 64);
#pragma unroll
    for (int q = 0; q < 16; ++q) {
        float4 a = Ri[q], b = Rf[q];
        wif[4 * q + 0] = v2f{a.x, b.x};
        wif[4 * q + 1] = v2f{a.y, b.y};
        wif[4 * q + 2] = v2f{a.z, b.z};
        wif[4 * q + 3] = v2f{a.w, b.w};
        float4 c = Rg[q], d = Ro[q];
        wgo[4 * q + 0] = v2f{c.x, d.x};
        wgo[4 * q + 1] = v2f{c.y, d.y};
        wgo[4 * q + 2] = v2f{c.z, d.z};
        wgo[4 * q + 3] = v2f{c.w, d.w};
    }
#pragma unroll
    for (int k = 0; k < 64; ++k) { pin(wif[k]); pin(wgo[k]); }
}

// ---------------------------------------------------------------------------
// Encoder: one wave per (variable n, batch b). Lane u owns hidden unit u and
// all 4 gate rows (256 VGPRs of weights, pinned; launch_bounds(64,1) gives
// the allocator the full 512-reg budget). No LDS, no barriers; h broadcast
// via v_readlane. Online-softmax temporal pooling fused.
// ---------------------------------------------------------------------------
__global__ __launch_bounds__(64, 1)
void enc_kernel(const float* __restrict__ X,
                const float* __restrict__ Wih,
                const float* __restrict__ Whh,
                const float* __restrict__ bias,
                const float* __restrict__ poolw,
                const float* __restrict__ poolb,
                float* __restrict__ Cws)   // [B][N][D]
{
    const int n = blockIdx.x >> 5;
    const int b = blockIdx.x & 31;
    const int u = threadIdx.x;

    v2f wif[64], wgo[64];
    load_gate_rows(Whh, n, u, wif, wgo);

    const float* Bn = bias + n * 256;
    v2f bif = {Bn[u],       Bn[u +  64]};
    v2f bgo = {Bn[u + 128], Bn[u + 192]};
    const float* Wn = Wih + n * 256;           // [4D][1]
    v2f xif = {Wn[u],       Wn[u +  64]};
    v2f xgo = {Wn[u + 128], Wn[u + 192]};
    pin(bif); pin(bgo); pin(xif); pin(xgo);
    const float pwu = poolw[n * DD + u];
    const float pbn = poolb[n];

    // x series for this (n,b): lane u holds t=u and t=u+64
    const float x0 = X[(size_t)b * (LL * NN) + (size_t)u * NN + n];
    const float x1 = X[(size_t)b * (LL * NN) + (size_t)(u + 64) * NN + n];

    float h = 0.0f, c = 0.0f;
    float m = -1e30f, s = 0.0f, pa = 0.0f;

#pragma unroll 1
    for (int t = 0; t < LL - 1; ++t) {
        const float xt = bcast((t < 64) ? x0 : x1, t & 63);
        v2f aif = __builtin_elementwise_fma(xif, v2f{xt, xt}, bif);
        v2f ago = __builtin_elementwise_fma(xgo, v2f{xt, xt}, bgo);
#pragma unroll
        for (int k = 0; k < 64; ++k) {
            const float hk = bcast(h, k);
            const v2f hh = {hk, hk};
            aif = __builtin_elementwise_fma(wif[k], hh, aif);
            ago = __builtin_elementwise_fma(wgo[k], hh, ago);
        }
        const float gi = sigmoidf_(aif.x), gf = sigmoidf_(aif.y);
        const float gg = tanhf_(ago.x),   go = sigmoidf_(ago.y);
        c = gf * c + gi * gg;
        h = go * tanhf_(c);

        // pooling score: full-wave reduce of h*pw
        float p = h * pwu;
#pragma unroll
        for (int off = 32; off >= 1; off >>= 1) p += __shfl_xor(p, off, 64);
        const float score = p + pbn;

        // online softmax (uniform across wave)
        const float mn   = fmaxf(m, score);
        const float corr = __expf(m - mn);
        const float wgt  = __expf(score - mn);
        s  = s * corr + wgt;
        pa = pa * corr + wgt * h;
        m  = mn;
    }

    Cws[(size_t)b * (NN * DD) + (size_t)n * DD + u] = pa / s;
}

// ---------------------------------------------------------------------------
// Attention per (b, h): qkv slice -> scores -> softmax -> o head slice.
// ---------------------------------------------------------------------------
__global__ __launch_bounds__(256)
void attn_kernel(const float* __restrict__ Cws,
                 const float* __restrict__ Wqkv,
                 const float* __restrict__ bqkv,
                 float* __restrict__ Ows)
{
    const int b = blockIdx.x >> 2;
    const int h = blockIdx.x & 3;
    const int tid = threadIdx.x;

    __shared__ float Cl[64][65];
    __shared__ float Wl[48][65];
    __shared__ float biasl[48];
    __shared__ float ql[64][17], kl[64][17], vl[64][17];
    __shared__ float sl[64][65];

    for (int i = tid; i < 64 * 64; i += 256)
        Cl[i >> 6][i & 63] = Cws[(size_t)b * (NN * DD) + i];
    for (int i = tid; i < 48 * 64; i += 256) {
        int row = i >> 6, col = i & 63;
        int grp = row >> 4, r = row & 15;
        Wl[row][col] = Wqkv[(size_t)(grp * 64 + h * 16 + r) * DD + col];
    }
    if (tid < 48) {
        int grp = tid >> 4, r = tid & 15;
        biasl[tid] = bqkv[grp * 64 + h * 16 + r];
    }
    __syncthreads();

    for (int i = tid; i < 3 * 64 * 16; i += 256) {
        int sec = i >> 10;
        int rem = i & 1023;
        int nn = rem >> 4, dh = rem & 15;
        float acc = biasl[sec * 16 + dh];
        const float* wr = &Wl[sec * 16 + dh][0];
#pragma unroll 16
        for (int k = 0; k < 64; ++k) acc = fmaf(Cl[nn][k], wr[k], acc);
        if      (sec == 0) ql[nn][dh] = acc;
        else if (sec == 1) kl[nn][dh] = acc;
        else               vl[nn][dh] = acc;
    }
    __syncthreads();

    for (int i = tid; i < 64 * 64; i += 256) {
        int nn = i >> 6, mm = i & 63;
        float acc = 0.0f;
#pragma unroll
        for (int d = 0; d < 16; ++d) acc = fmaf(ql[nn][d], kl[mm][d], acc);
        sl[nn][mm] = acc * 0.25f;
    }
    __syncthreads();

    if (tid < 64) {
        float mx = -1e30f;
        for (int mm = 0; mm < 64; ++mm) mx = fmaxf(mx, sl[tid][mm]);
        float ss = 0.0f;
        for (int mm = 0; mm < 64; ++mm) {
            float e = __expf(sl[tid][mm] - mx);
            sl[tid][mm] = e;
            ss += e;
        }
        float inv = 1.0f / ss;
        for (int mm = 0; mm < 64; ++mm) sl[tid][mm] *= inv;
    }
    __syncthreads();

    for (int i = tid; i < 64 * 16; i += 256) {
        int nn = i >> 4, dh = i & 15;
        float acc = 0.0f;
#pragma unroll 16
        for (int mm = 0; mm < 64; ++mm) acc = fmaf(sl[nn][mm], vl[mm][dh], acc);
        Ows[(size_t)b * (NN * DD) + (size_t)nn * DD + h * 16 + dh] = acc;
    }
}

__global__ __launch_bounds__(256)
void proj_kernel(const float* __restrict__ Ows,
                 const float* __restrict__ Wo,
                 const float* __restrict__ bo,
                 float* __restrict__ Cstar)
{
    const int b = blockIdx.x;
    const int tid = threadIdx.x;
    __shared__ float Ol[64][65];
    __shared__ float Wl[64][65];

    for (int i = tid; i < 64 * 64; i += 256) {
        Ol[i >> 6][i & 63] = Ows[(size_t)b * (NN * DD) + i];
        Wl[i >> 6][i & 63] = Wo[i];
    }
    __syncthreads();

    for (int i = tid; i < 64 * 64; i += 256) {
        int nn = i >> 6, d = i & 63;
        float acc = bo[d];
#pragma unroll 16
        for (int k = 0; k < 64; ++k) acc = fmaf(Ol[nn][k], Wl[d][k], acc);
        Cstar[(size_t)b * (NN * DD) + i] = acc;
    }
}

// ---------------------------------------------------------------------------
// Decoder init: h0/c0 = tanh(Cs @ W^T + b) per (n, b). One wave per (n,b).
// ---------------------------------------------------------------------------
__global__ __launch_bounds__(64)
void dec_init_kernel(const float* __restrict__ Cstar,
                     const float* __restrict__ WhI,
                     const float* __restrict__ bhI,
                     const float* __restrict__ WcI,
                     const float* __restrict__ bcI,
                     float* __restrict__ H0,
                     float* __restrict__ C0)
{
    const int n = blockIdx.x >> 5;
    const int b = blockIdx.x & 31;
    const int u = threadIdx.x;

    const float cs = Cstar[(size_t)b * (NN * DD) + (size_t)n * DD + u];
    const float4* Rh = reinterpret_cast<const float4*>(WhI + ((size_t)n * DD + u) * DD);
    const float4* Rc = reinterpret_cast<const float4*>(WcI + ((size_t)n * DD + u) * DD);
    float ah = bhI[n * DD + u];
    float ac = bcI[n * DD + u];
#pragma unroll
    for (int q = 0; q < 16; ++q) {
        const float4 wh = Rh[q], wc = Rc[q];
        float k0 = bcast(cs, 4 * q + 0);
        float k1 = bcast(cs, 4 * q + 1);
        float k2 = bcast(cs, 4 * q + 2);
        float k3 = bcast(cs, 4 * q + 3);
        ah = fmaf(wh.x, k0, ah); ah = fmaf(wh.y, k1, ah);
        ah = fmaf(wh.z, k2, ah); ah = fmaf(wh.w, k3, ah);
        ac = fmaf(wc.x, k0, ac); ac = fmaf(wc.y, k1, ac);
        ac = fmaf(wc.z, k2, ac); ac = fmaf(wc.w, k3, ac);
    }
    const size_t idx = ((size_t)n * BB + b) * DD + u;
    H0[idx] = tanhf_(ah);
    C0[idx] = tanhf_(ac);
}

// ---------------------------------------------------------------------------
// Decoder: one wave per (n, b); zero inputs; per-step y = h.ow + ob.
// ---------------------------------------------------------------------------
__global__ __launch_bounds__(64, 1)
void dec_kernel(const float* __restrict__ Whh,
                const float* __restrict__ bias,
                const float* __restrict__ ow,
                const float* __restrict__ ob,
                const float* __restrict__ H0,
                const float* __restrict__ C0,
                float* __restrict__ recon,        // [B][L-1][N]
                float* __restrict__ pred)         // [B][N]
{
    const int n = blockIdx.x >> 5;
    const int b = blockIdx.x & 31;
    const int u = threadIdx.x;

    v2f wif[64], wgo[64];
    load_gate_rows(Whh, n, u, wif, wgo);

    const float* Bn = bias + n * 256;
    v2f bif = {Bn[u],       Bn[u +  64]};
    v2f bgo = {Bn[u + 128], Bn[u + 192]};
    pin(bif); pin(bgo);
    const float owu = ow[n * DD + u];
    const float obn = ob[n];

    const size_t idx = ((size_t)n * BB + b) * DD + u;
    float h = H0[idx];
    float c = C0[idx];

#pragma unroll 1
    for (int t = 0; t < LL; ++t) {
        v2f aif = bif, ago = bgo;
#pragma unroll
        for (int k = 0; k < 64; ++k) {
            const float hk = bcast(h, k);
            const v2f hh = {hk, hk};
            aif = __builtin_elementwise_fma(wif[k], hh, aif);
            ago = __builtin_elementwise_fma(wgo[k], hh, ago);
        }
        const float gi = sigmoidf_(aif.x), gf = sigmoidf_(aif.y);
        const float gg = tanhf_(ago.x),   go = sigmoidf_(ago.y);
        c = gf * c + gi * gg;
        h = go * tanhf_(c);

        float p = h * owu;
#pragma unroll
        for (int off = 32; off >= 1; off >>= 1) p += __shfl_xor(p, off, 64);
        if (u == 0) {
            const float y = p + obn;
            if (t < LL - 1)
                recon[(size_t)b * ((LL - 1) * NN) + (size_t)t * NN + n] = y;
            else
                pred[(size_t)b * NN + n] = y;
        }
    }
}

extern "C" void kernel_launch(void* const* d_in, const int* in_sizes, int n_in,
                              void* d_out, int out_size, void* d_ws, size_t ws_size,
                              hipStream_t stream) {
    (void)in_sizes; (void)n_in; (void)out_size; (void)ws_size;

    const float* X         = (const float*)d_in[0];
    const float* enc_Wih   = (const float*)d_in[1];
    const float* enc_Whh   = (const float*)d_in[2];
    const float* enc_b     = (const float*)d_in[3];
    const float* pool_w    = (const float*)d_in[4];
    const float* pool_b    = (const float*)d_in[5];
    const float* attn_Wqkv = (const float*)d_in[6];
    const float* attn_bqkv = (const float*)d_in[7];
    const float* attn_Wo   = (const float*)d_in[8];
    const float* attn_bo   = (const float*)d_in[9];
    // d_in[10] = dec_Wih: multiplied by all-zero inputs -> unused
    const float* dec_Whh   = (const float*)d_in[11];
    const float* dec_b     = (const float*)d_in[12];
    const float* init_h_W  = (const float*)d_in[13];
    const float* init_h_b  = (const float*)d_in[14];
    const float* init_c_W  = (const float*)d_in[15];
    const float* init_c_b  = (const float*)d_in[16];
    const float* out_w     = (const float*)d_in[17];
    const float* out_b     = (const float*)d_in[18];

    float* out   = (float*)d_out;
    float* recon = out;                                     // B*(L-1)*N
    float* pred  = out + (size_t)BB * (LL - 1) * NN;        // B*N
    float* cstar = pred + (size_t)BB * NN;                  // B*N*D

    float* Cws = (float*)d_ws;                              // [B][N][D]
    float* Ows = Cws + (size_t)BB * NN * DD;                // [B][N][D]
    // After proj, Cws/Ows are dead -> reuse for H0/C0 ([N][B][D] each)
    float* H0 = Cws;
    float* C0 = Ows;

    enc_kernel<<<dim3(NN * BB), dim3(64), 0, stream>>>(
        X, enc_Wih, enc_Whh, enc_b, pool_w, pool_b, Cws);

    attn_kernel<<<dim3(BB * HH), dim3(256), 0, stream>>>(
        Cws, attn_Wqkv, attn_bqkv, Ows);

    proj_kernel<<<dim3(BB), dim3(256), 0, stream>>>(
        Ows, attn_Wo, attn_bo, cstar);

    dec_init_kernel<<<dim3(NN * BB), dim3(64), 0, stream>>>(
        cstar, init_h_W, init_h_b, init_c_W, init_c_b, H0, C0);

    dec_kernel<<<dim3(NN * BB), dim3(64), 0, stream>>>(
        dec_Whh, dec_b, out_w, out_b, H0, C0, recon, pred);
}

// Round 8
// 580.804 us; speedup vs baseline: 1.0035x; 1.0035x over previous
//
#include <hip/hip_runtime.h>
#include <cstddef>

// Problem constants (reference: B=32, L=128, N=64, D=64, H=4, DH=16)
#define BB   32
#define LL   128
#define NN   64
#define DD   64
#define HH   4

typedef float v2f __attribute__((ext_vector_type(2)));

__device__ __forceinline__ float bcast(float v, int l) {
    return __int_as_float(__builtin_amdgcn_readlane(__float_as_int(v), l));
}
__device__ __forceinline__ float sigmoidf_(float x) {
    return 1.0f / (1.0f + __expf(-x));
}
__device__ __forceinline__ float tanhf_(float x) {
    float e = __expf(2.0f * x);
    return 1.0f - 2.0f / (e + 1.0f);
}
__device__ __forceinline__ void pin(v2f& v) {
    asm volatile("" : "+v"(v));
}

// ---------------------------------------------------------------------------
// R7 post-mortem: v2f wif[64]/wgo[64] per-thread ARRAYS were never promoted
// to registers (scratch-resident; pin was a no-op; VGPR stuck at 144; every
// step re-read 1KB/lane from scratch through L1/L2 -> latency-bound at 50%
// VALUBusy). Fix: 128 individually NAMED v2f values via X-macros — SSA from
// birth, no alloca, nothing for the promoter to reject.
// ---------------------------------------------------------------------------
#define LIST64(X) \
  X(0)  X(1)  X(2)  X(3)  X(4)  X(5)  X(6)  X(7)  \
  X(8)  X(9)  X(10) X(11) X(12) X(13) X(14) X(15) \
  X(16) X(17) X(18) X(19) X(20) X(21) X(22) X(23) \
  X(24) X(25) X(26) X(27) X(28) X(29) X(30) X(31) \
  X(32) X(33) X(34) X(35) X(36) X(37) X(38) X(39) \
  X(40) X(41) X(42) X(43) X(44) X(45) X(46) X(47) \
  X(48) X(49) X(50) X(51) X(52) X(53) X(54) X(55) \
  X(56) X(57) X(58) X(59) X(60) X(61) X(62) X(63)

// declare 128 named weight pairs
#define DECLW(k) v2f wif##k, wgo##k;
// load: row pointers Ri/Rf/Rg/Ro must be in scope (consecutive k -> compiler
// merges into dwordx4)
#define LOADW(k) wif##k = v2f{Ri[k], Rf[k]}; wgo##k = v2f{Rg[k], Ro[k]};
// pin after load (true SSA values now -> forces VGPR residency)
#define PINW(k)  pin(wif##k); pin(wgo##k);
// one k-step of the gate matvec: aif/ago/h in scope
#define FMAK(k)  { const float hk_##k = bcast(h, k);                          \
                   const v2f hh_##k = {hk_##k, hk_##k};                       \
                   aif = __builtin_elementwise_fma(wif##k, hh_##k, aif);      \
                   ago = __builtin_elementwise_fma(wgo##k, hh_##k, ago); }

// ---------------------------------------------------------------------------
// Encoder: one wave per (variable n, batch b). Lane u owns hidden unit u and
// all 4 gate rows (i,f,g,o) = 256 VGPRs of weights, named + pinned.
// No LDS, no barriers; h broadcast via v_readlane. Online-softmax pooling.
// ---------------------------------------------------------------------------
__global__ __launch_bounds__(64, 1)
void enc_kernel(const float* __restrict__ X,
                const float* __restrict__ Wih,
                const float* __restrict__ Whh,
                const float* __restrict__ bias,
                const float* __restrict__ poolw,
                const float* __restrict__ poolb,
                float* __restrict__ Cws)   // [B][N][D]
{
    const int n = blockIdx.x >> 5;
    const int b = blockIdx.x & 31;
    const int u = threadIdx.x;

    const float* Ri = Whh + ((size_t)n * 256 + u) * 64;
    const float* Rf = Ri + 64 * 64;
    const float* Rg = Ri + 128 * 64;
    const float* Ro = Ri + 192 * 64;

    LIST64(DECLW)
    LIST64(LOADW)
    LIST64(PINW)

    const float* Bn = bias + n * 256;
    v2f bif = {Bn[u],       Bn[u +  64]};
    v2f bgo = {Bn[u + 128], Bn[u + 192]};
    const float* Wn = Wih + n * 256;           // [4D][1]
    v2f xif = {Wn[u],       Wn[u +  64]};
    v2f xgo = {Wn[u + 128], Wn[u + 192]};
    pin(bif); pin(bgo); pin(xif); pin(xgo);
    const float pwu = poolw[n * DD + u];
    const float pbn = poolb[n];

    // x series for this (n,b): lane u holds t=u and t=u+64
    const float x0 = X[(size_t)b * (LL * NN) + (size_t)u * NN + n];
    const float x1 = X[(size_t)b * (LL * NN) + (size_t)(u + 64) * NN + n];

    float h = 0.0f, c = 0.0f;
    float m = -1e30f, s = 0.0f, pa = 0.0f;

#pragma unroll 1
    for (int t = 0; t < LL - 1; ++t) {
        const float xt = bcast((t < 64) ? x0 : x1, t & 63);
        v2f aif = __builtin_elementwise_fma(xif, v2f{xt, xt}, bif);
        v2f ago = __builtin_elementwise_fma(xgo, v2f{xt, xt}, bgo);

        LIST64(FMAK)

        const float gi = sigmoidf_(aif.x), gf = sigmoidf_(aif.y);
        const float gg = tanhf_(ago.x),   go = sigmoidf_(ago.y);
        c = gf * c + gi * gg;
        h = go * tanhf_(c);

        // pooling score: full-wave reduce of h*pw
        float p = h * pwu;
#pragma unroll
        for (int off = 32; off >= 1; off >>= 1) p += __shfl_xor(p, off, 64);
        const float score = p + pbn;

        // online softmax (uniform across wave)
        const float mn   = fmaxf(m, score);
        const float corr = __expf(m - mn);
        const float wgt  = __expf(score - mn);
        s  = s * corr + wgt;
        pa = pa * corr + wgt * h;
        m  = mn;
    }

    Cws[(size_t)b * (NN * DD) + (size_t)n * DD + u] = pa / s;
}

// ---------------------------------------------------------------------------
// Attention per (b, h): qkv slice -> scores -> softmax -> o head slice.
// ---------------------------------------------------------------------------
__global__ __launch_bounds__(256)
void attn_kernel(const float* __restrict__ Cws,
                 const float* __restrict__ Wqkv,
                 const float* __restrict__ bqkv,
                 float* __restrict__ Ows)
{
    const int b = blockIdx.x >> 2;
    const int h = blockIdx.x & 3;
    const int tid = threadIdx.x;

    __shared__ float Cl[64][65];
    __shared__ float Wl[48][65];
    __shared__ float biasl[48];
    __shared__ float ql[64][17], kl[64][17], vl[64][17];
    __shared__ float sl[64][65];

    for (int i = tid; i < 64 * 64; i += 256)
        Cl[i >> 6][i & 63] = Cws[(size_t)b * (NN * DD) + i];
    for (int i = tid; i < 48 * 64; i += 256) {
        int row = i >> 6, col = i & 63;
        int grp = row >> 4, r = row & 15;
        Wl[row][col] = Wqkv[(size_t)(grp * 64 + h * 16 + r) * DD + col];
    }
    if (tid < 48) {
        int grp = tid >> 4, r = tid & 15;
        biasl[tid] = bqkv[grp * 64 + h * 16 + r];
    }
    __syncthreads();

    for (int i = tid; i < 3 * 64 * 16; i += 256) {
        int sec = i >> 10;
        int rem = i & 1023;
        int nn = rem >> 4, dh = rem & 15;
        float acc = biasl[sec * 16 + dh];
        const float* wr = &Wl[sec * 16 + dh][0];
#pragma unroll 16
        for (int k = 0; k < 64; ++k) acc = fmaf(Cl[nn][k], wr[k], acc);
        if      (sec == 0) ql[nn][dh] = acc;
        else if (sec == 1) kl[nn][dh] = acc;
        else               vl[nn][dh] = acc;
    }
    __syncthreads();

    for (int i = tid; i < 64 * 64; i += 256) {
        int nn = i >> 6, mm = i & 63;
        float acc = 0.0f;
#pragma unroll
        for (int d = 0; d < 16; ++d) acc = fmaf(ql[nn][d], kl[mm][d], acc);
        sl[nn][mm] = acc * 0.25f;
    }
    __syncthreads();

    if (tid < 64) {
        float mx = -1e30f;
        for (int mm = 0; mm < 64; ++mm) mx = fmaxf(mx, sl[tid][mm]);
        float ss = 0.0f;
        for (int mm = 0; mm < 64; ++mm) {
            float e = __expf(sl[tid][mm] - mx);
            sl[tid][mm] = e;
            ss += e;
        }
        float inv = 1.0f / ss;
        for (int mm = 0; mm < 64; ++mm) sl[tid][mm] *= inv;
    }
    __syncthreads();

    for (int i = tid; i < 64 * 16; i += 256) {
        int nn = i >> 4, dh = i & 15;
        float acc = 0.0f;
#pragma unroll 16
        for (int mm = 0; mm < 64; ++mm) acc = fmaf(sl[nn][mm], vl[mm][dh], acc);
        Ows[(size_t)b * (NN * DD) + (size_t)nn * DD + h * 16 + dh] = acc;
    }
}

__global__ __launch_bounds__(256)
void proj_kernel(const float* __restrict__ Ows,
                 const float* __restrict__ Wo,
                 const float* __restrict__ bo,
                 float* __restrict__ Cstar)
{
    const int b = blockIdx.x;
    const int tid = threadIdx.x;
    __shared__ float Ol[64][65];
    __shared__ float Wl[64][65];

    for (int i = tid; i < 64 * 64; i += 256) {
        Ol[i >> 6][i & 63] = Ows[(size_t)b * (NN * DD) + i];
        Wl[i >> 6][i & 63] = Wo[i];
    }
    __syncthreads();

    for (int i = tid; i < 64 * 64; i += 256) {
        int nn = i >> 6, d = i & 63;
        float acc = bo[d];
#pragma unroll 16
        for (int k = 0; k < 64; ++k) acc = fmaf(Ol[nn][k], Wl[d][k], acc);
        Cstar[(size_t)b * (NN * DD) + i] = acc;
    }
}

// ---------------------------------------------------------------------------
// Decoder init: h0/c0 = tanh(Cs @ W^T + b) per (n, b). One wave per (n,b).
// ---------------------------------------------------------------------------
__global__ __launch_bounds__(64)
void dec_init_kernel(const float* __restrict__ Cstar,
                     const float* __restrict__ WhI,
                     const float* __restrict__ bhI,
                     const float* __restrict__ WcI,
                     const float* __restrict__ bcI,
                     float* __restrict__ H0,
                     float* __restrict__ C0)
{
    const int n = blockIdx.x >> 5;
    const int b = blockIdx.x & 31;
    const int u = threadIdx.x;

    const float cs = Cstar[(size_t)b * (NN * DD) + (size_t)n * DD + u];
    const float4* Rh = reinterpret_cast<const float4*>(WhI + ((size_t)n * DD + u) * DD);
    const float4* Rc = reinterpret_cast<const float4*>(WcI + ((size_t)n * DD + u) * DD);
    float ah = bhI[n * DD + u];
    float ac = bcI[n * DD + u];
#pragma unroll
    for (int q = 0; q < 16; ++q) {
        const float4 wh = Rh[q], wc = Rc[q];
        float k0 = bcast(cs, 4 * q + 0);
        float k1 = bcast(cs, 4 * q + 1);
        float k2 = bcast(cs, 4 * q + 2);
        float k3 = bcast(cs, 4 * q + 3);
        ah = fmaf(wh.x, k0, ah); ah = fmaf(wh.y, k1, ah);
        ah = fmaf(wh.z, k2, ah); ah = fmaf(wh.w, k3, ah);
        ac = fmaf(wc.x, k0, ac); ac = fmaf(wc.y, k1, ac);
        ac = fmaf(wc.z, k2, ac); ac = fmaf(wc.w, k3, ac);
    }
    const size_t idx = ((size_t)n * BB + b) * DD + u;
    H0[idx] = tanhf_(ah);
    C0[idx] = tanhf_(ac);
}

// ---------------------------------------------------------------------------
// Decoder: one wave per (n, b); zero inputs; per-step y = h.ow + ob.
// Same named-register weight scheme as the encoder.
// ---------------------------------------------------------------------------
__global__ __launch_bounds__(64, 1)
void dec_kernel(const float* __restrict__ Whh,
                const float* __restrict__ bias,
                const float* __restrict__ ow,
                const float* __restrict__ ob,
                const float* __restrict__ H0,
                const float* __restrict__ C0,
                float* __restrict__ recon,        // [B][L-1][N]
                float* __restrict__ pred)         // [B][N]
{
    const int n = blockIdx.x >> 5;
    const int b = blockIdx.x & 31;
    const int u = threadIdx.x;

    const float* Ri = Whh + ((size_t)n * 256 + u) * 64;
    const float* Rf = Ri + 64 * 64;
    const float* Rg = Ri + 128 * 64;
    const float* Ro = Ri + 192 * 64;

    LIST64(DECLW)
    LIST64(LOADW)
    LIST64(PINW)

    const float* Bn = bias + n * 256;
    v2f bif = {Bn[u],       Bn[u +  64]};
    v2f bgo = {Bn[u + 128], Bn[u + 192]};
    pin(bif); pin(bgo);
    const float owu = ow[n * DD + u];
    const float obn = ob[n];

    const size_t idx = ((size_t)n * BB + b) * DD + u;
    float h = H0[idx];
    float c = C0[idx];

#pragma unroll 1
    for (int t = 0; t < LL; ++t) {
        v2f aif = bif, ago = bgo;

        LIST64(FMAK)

        const float gi = sigmoidf_(aif.x), gf = sigmoidf_(aif.y);
        const float gg = tanhf_(ago.x),   go = sigmoidf_(ago.y);
        c = gf * c + gi * gg;
        h = go * tanhf_(c);

        float p = h * owu;
#pragma unroll
        for (int off = 32; off >= 1; off >>= 1) p += __shfl_xor(p, off, 64);
        if (u == 0) {
            const float y = p + obn;
            if (t < LL - 1)
                recon[(size_t)b * ((LL - 1) * NN) + (size_t)t * NN + n] = y;
            else
                pred[(size_t)b * NN + n] = y;
        }
    }
}

extern "C" void kernel_launch(void* const* d_in, const int* in_sizes, int n_in,
                              void* d_out, int out_size, void* d_ws, size_t ws_size,
                              hipStream_t stream) {
    (void)in_sizes; (void)n_in; (void)out_size; (void)ws_size;

    const float* X         = (const float*)d_in[0];
    const float* enc_Wih   = (const float*)d_in[1];
    const float* enc_Whh   = (const float*)d_in[2];
    const float* enc_b     = (const float*)d_in[3];
    const float* pool_w    = (const float*)d_in[4];
    const float* pool_b    = (const float*)d_in[5];
    const float* attn_Wqkv = (const float*)d_in[6];
    const float* attn_bqkv = (const float*)d_in[7];
    const float* attn_Wo   = (const float*)d_in[8];
    const float* attn_bo   = (const float*)d_in[9];
    // d_in[10] = dec_Wih: multiplied by all-zero inputs -> unused
    const float* dec_Whh   = (const float*)d_in[11];
    const float* dec_b     = (const float*)d_in[12];
    const float* init_h_W  = (const float*)d_in[13];
    const float* init_h_b  = (const float*)d_in[14];
    const float* init_c_W  = (const float*)d_in[15];
    const float* init_c_b  = (const float*)d_in[16];
    const float* out_w     = (const float*)d_in[17];
    const float* out_b     = (const float*)d_in[18];

    float* out   = (float*)d_out;
    float* recon = out;                                     // B*(L-1)*N
    float* pred  = out + (size_t)BB * (LL - 1) * NN;        // B*N
    float* cstar = pred + (size_t)BB * NN;                  // B*N*D

    float* Cws = (float*)d_ws;                              // [B][N][D]
    float* Ows = Cws + (size_t)BB * NN * DD;                // [B][N][D]
    // After proj, Cws/Ows are dead -> reuse for H0/C0 ([N][B][D] each)
    float* H0 = Cws;
    float* C0 = Ows;

    enc_kernel<<<dim3(NN * BB), dim3(64), 0, stream>>>(
        X, enc_Wih, enc_Whh, enc_b, pool_w, pool_b, Cws);

    attn_kernel<<<dim3(BB * HH), dim3(256), 0, stream>>>(
        Cws, attn_Wqkv, attn_bqkv, Ows);

    proj_kernel<<<dim3(BB), dim3(256), 0, stream>>>(
        Ows, attn_Wo, attn_bo, cstar);

    dec_init_kernel<<<dim3(NN * BB), dim3(64), 0, stream>>>(
        cstar, init_h_W, init_h_b, init_c_W, init_c_b, H0, C0);

    dec_kernel<<<dim3(NN * BB), dim3(64), 0, stream>>>(
        dec_Whh, dec_b, out_w, out_b, H0, C0, recon, pred);
}

// Round 9
// 528.417 us; speedup vs baseline: 1.1030x; 1.0991x over previous
//
#include <hip/hip_runtime.h>
#include <cstddef>

// Problem constants (reference: B=32, L=128, N=64, D=64, H=4, DH=16)
#define BB   32
#define LL   128
#define NN   64
#define DD   64
#define HH   4

typedef float v2f __attribute__((ext_vector_type(2)));

__device__ __forceinline__ float bcast(float v, int l) {
    return __int_as_float(__builtin_amdgcn_readlane(__float_as_int(v), l));
}
__device__ __forceinline__ float sigmoidf_(float x) {
    return 1.0f / (1.0f + __expf(-x));
}
__device__ __forceinline__ float tanhf_(float x) {
    float e = __expf(2.0f * x);
    return 1.0f - 2.0f / (e + 1.0f);
}
__device__ __forceinline__ void pin(v2f& v) {
    asm volatile("" : "+v"(v));
}

// ---------------------------------------------------------------------------
// R8 post-mortem: 256 weight VGPRs/lane + ~40 working > 256 arch-VGPR VALU
// encoding limit -> allocator MUST spill half the weights; all pin/naming
// tricks were no-ops (VGPR stuck at 144, L2-bound on spill reloads, 291us).
// Fix: split K across TWO waves per chain. Lane u of wave w holds 4 gate rows
// x 32 k = 128 VGPRs (fits). Two batches share the weights. Partials
// exchanged via LDS once per step; each wave finalizes its own batch.
// ---------------------------------------------------------------------------
#define KLIST(X) X(0) X(1) X(2) X(3) X(4) X(5) X(6) X(7) \
                 X(8) X(9) X(10) X(11) X(12) X(13) X(14) X(15)

#define DECLW(j) v2f wifA##j, wifB##j, wgoA##j, wgoB##j;
#define LOADW(j) \
    wifA##j = v2f{Ri[2*(j)],   Rf[2*(j)]};   \
    wifB##j = v2f{Ri[2*(j)+1], Rf[2*(j)+1]}; \
    wgoA##j = v2f{Rg[2*(j)],   Ro[2*(j)]};   \
    wgoB##j = v2f{Rg[2*(j)+1], Ro[2*(j)+1]};
#define PINW(j) pin(wifA##j); pin(wifB##j); pin(wgoA##j); pin(wgoB##j);

// One j handles k = kbase+2j (chain A) and kbase+2j+1 (chain B) for both
// batches. 4 readlane + 8 v_pk_fma_f32.
#define FMAK(j) { \
    const float ha0 = bcast(h0, kbase + 2*(j)); \
    const float hb0 = bcast(h0, kbase + 2*(j) + 1); \
    const float ha1 = bcast(h1, kbase + 2*(j)); \
    const float hb1 = bcast(h1, kbase + 2*(j) + 1); \
    aifA0 = __builtin_elementwise_fma(wifA##j, v2f{ha0,ha0}, aifA0); \
    agoA0 = __builtin_elementwise_fma(wgoA##j, v2f{ha0,ha0}, agoA0); \
    aifB0 = __builtin_elementwise_fma(wifB##j, v2f{hb0,hb0}, aifB0); \
    agoB0 = __builtin_elementwise_fma(wgoB##j, v2f{hb0,hb0}, agoB0); \
    aifA1 = __builtin_elementwise_fma(wifA##j, v2f{ha1,ha1}, aifA1); \
    agoA1 = __builtin_elementwise_fma(wgoA##j, v2f{ha1,ha1}, agoA1); \
    aifB1 = __builtin_elementwise_fma(wifB##j, v2f{hb1,hb1}, aifB1); \
    agoB1 = __builtin_elementwise_fma(wgoB##j, v2f{hb1,hb1}, agoB1); }

// ---------------------------------------------------------------------------
// Encoder: block = (n, batch pair), 2 waves (k-halves). Online-softmax
// temporal attention pooling; wave w owns batch (2*bg + w) for the
// nonlinearity/pooling phase.
// ---------------------------------------------------------------------------
__global__ __launch_bounds__(128, 2)
void enc_kernel(const float* __restrict__ X,
                const float* __restrict__ Wih,
                const float* __restrict__ Whh,
                const float* __restrict__ bias,
                const float* __restrict__ poolw,
                const float* __restrict__ poolb,
                float* __restrict__ Cws)   // [B][N][D]
{
    const int n   = blockIdx.x >> 4;
    const int bg  = blockIdx.x & 15;
    const int tid = threadIdx.x;
    const int w   = tid >> 6;          // k-half / owned batch
    const int u   = tid & 63;          // hidden unit
    const int kbase = w << 5;
    const int bbm = 2 * bg + w;        // this wave's batch

    __shared__ float4 part[2][2][64];  // [wave][batch][unit]
    __shared__ float  hx[2][64];       // [batch][unit]

    const float* Ri = Whh + (size_t)n * 16384 + (size_t)u * 64 + kbase;
    const float* Rf = Ri + 64 * 64;
    const float* Rg = Ri + 128 * 64;
    const float* Ro = Ri + 192 * 64;

    KLIST(DECLW)
    KLIST(LOADW)
    KLIST(PINW)

    const float* Bn = bias + n * 256;
    v2f bif = {Bn[u],       Bn[u +  64]};
    v2f bgo = {Bn[u + 128], Bn[u + 192]};
    const float* Wn = Wih + n * 256;
    v2f xif = {Wn[u],       Wn[u +  64]};
    v2f xgo = {Wn[u + 128], Wn[u + 192]};
    pin(bif); pin(bgo); pin(xif); pin(xgo);

    const float pwu = poolw[n * DD + u];
    const float pbn = poolb[n];

    // x series for MY batch: lane u holds t=u and t=u+64
    const float xm0 = X[(size_t)bbm * (LL * NN) + (size_t)u * NN + n];
    const float xm1 = X[(size_t)bbm * (LL * NN) + (size_t)(u + 64) * NN + n];

    float h0 = 0.0f, h1 = 0.0f, cm = 0.0f;
    float m = -1e30f, s = 0.0f, pa = 0.0f;

#pragma unroll 1
    for (int t = 0; t < LL - 1; ++t) {
        // bias + x*Wih goes into MY wave's partial for MY batch only
        const float xt = bcast((t < 64) ? xm0 : xm1, t & 63);
        const v2f ini_if = __builtin_elementwise_fma(xif, v2f{xt, xt}, bif);
        const v2f ini_go = __builtin_elementwise_fma(xgo, v2f{xt, xt}, bgo);
        const v2f z = {0.0f, 0.0f};
        v2f aifA0 = (w == 0) ? ini_if : z;
        v2f agoA0 = (w == 0) ? ini_go : z;
        v2f aifA1 = (w == 0) ? z : ini_if;
        v2f agoA1 = (w == 0) ? z : ini_go;
        v2f aifB0 = z, agoB0 = z, aifB1 = z, agoB1 = z;

        KLIST(FMAK)

        const v2f aif0 = aifA0 + aifB0, ago0 = agoA0 + agoB0;
        const v2f aif1 = aifA1 + aifB1, ago1 = agoA1 + agoB1;

        part[w][0][u] = float4{aif0.x, aif0.y, ago0.x, ago0.y};
        part[w][1][u] = float4{aif1.x, aif1.y, ago1.x, ago1.y};
        __syncthreads();
        const float4 po = part[w ^ 1][w][u];   // partner's partial, my batch
        const v2f mine_if = (w == 0) ? aif0 : aif1;
        const v2f mine_go = (w == 0) ? ago0 : ago1;
        const v2f gif = mine_if + v2f{po.x, po.y};
        const v2f ggo = mine_go + v2f{po.z, po.w};

        const float gi = sigmoidf_(gif.x), gf = sigmoidf_(gif.y);
        const float gg = tanhf_(ggo.x),    go = sigmoidf_(ggo.y);
        cm = gf * cm + gi * gg;
        const float hm = go * tanhf_(cm);

        // pooling for MY batch (wave-local reduce)
        float p = hm * pwu;
#pragma unroll
        for (int off = 32; off >= 1; off >>= 1) p += __shfl_xor(p, off, 64);
        const float score = p + pbn;
        const float mn   = fmaxf(m, score);
        const float corr = __expf(m - mn);
        const float wgt  = __expf(score - mn);
        s  = s * corr + wgt;
        pa = pa * corr + wgt * hm;
        m  = mn;

        hx[w][u] = hm;
        __syncthreads();
        const float ho = hx[w ^ 1][u];
        h0 = (w == 0) ? hm : ho;
        h1 = (w == 0) ? ho : hm;
    }

    Cws[(size_t)bbm * (NN * DD) + (size_t)n * DD + u] = pa / s;
}

// ---------------------------------------------------------------------------
// Attention per (b, h): qkv slice -> scores -> softmax -> o head slice.
// ---------------------------------------------------------------------------
__global__ __launch_bounds__(256)
void attn_kernel(const float* __restrict__ Cws,
                 const float* __restrict__ Wqkv,
                 const float* __restrict__ bqkv,
                 float* __restrict__ Ows)
{
    const int b = blockIdx.x >> 2;
    const int h = blockIdx.x & 3;
    const int tid = threadIdx.x;

    __shared__ float Cl[64][65];
    __shared__ float Wl[48][65];
    __shared__ float biasl[48];
    __shared__ float ql[64][17], kl[64][17], vl[64][17];
    __shared__ float sl[64][65];

    for (int i = tid; i < 64 * 64; i += 256)
        Cl[i >> 6][i & 63] = Cws[(size_t)b * (NN * DD) + i];
    for (int i = tid; i < 48 * 64; i += 256) {
        int row = i >> 6, col = i & 63;
        int grp = row >> 4, r = row & 15;
        Wl[row][col] = Wqkv[(size_t)(grp * 64 + h * 16 + r) * DD + col];
    }
    if (tid < 48) {
        int grp = tid >> 4, r = tid & 15;
        biasl[tid] = bqkv[grp * 64 + h * 16 + r];
    }
    __syncthreads();

    for (int i = tid; i < 3 * 64 * 16; i += 256) {
        int sec = i >> 10;
        int rem = i & 1023;
        int nn = rem >> 4, dh = rem & 15;
        float acc = biasl[sec * 16 + dh];
        const float* wr = &Wl[sec * 16 + dh][0];
#pragma unroll 16
        for (int k = 0; k < 64; ++k) acc = fmaf(Cl[nn][k], wr[k], acc);
        if      (sec == 0) ql[nn][dh] = acc;
        else if (sec == 1) kl[nn][dh] = acc;
        else               vl[nn][dh] = acc;
    }
    __syncthreads();

    for (int i = tid; i < 64 * 64; i += 256) {
        int nn = i >> 6, mm = i & 63;
        float acc = 0.0f;
#pragma unroll
        for (int d = 0; d < 16; ++d) acc = fmaf(ql[nn][d], kl[mm][d], acc);
        sl[nn][mm] = acc * 0.25f;
    }
    __syncthreads();

    if (tid < 64) {
        float mx = -1e30f;
        for (int mm = 0; mm < 64; ++mm) mx = fmaxf(mx, sl[tid][mm]);
        float ss = 0.0f;
        for (int mm = 0; mm < 64; ++mm) {
            float e = __expf(sl[tid][mm] - mx);
            sl[tid][mm] = e;
            ss += e;
        }
        float inv = 1.0f / ss;
        for (int mm = 0; mm < 64; ++mm) sl[tid][mm] *= inv;
    }
    __syncthreads();

    for (int i = tid; i < 64 * 16; i += 256) {
        int nn = i >> 4, dh = i & 15;
        float acc = 0.0f;
#pragma unroll 16
        for (int mm = 0; mm < 64; ++mm) acc = fmaf(sl[nn][mm], vl[mm][dh], acc);
        Ows[(size_t)b * (NN * DD) + (size_t)nn * DD + h * 16 + dh] = acc;
    }
}

__global__ __launch_bounds__(256)
void proj_kernel(const float* __restrict__ Ows,
                 const float* __restrict__ Wo,
                 const float* __restrict__ bo,
                 float* __restrict__ Cstar)
{
    const int b = blockIdx.x;
    const int tid = threadIdx.x;
    __shared__ float Ol[64][65];
    __shared__ float Wl[64][65];

    for (int i = tid; i < 64 * 64; i += 256) {
        Ol[i >> 6][i & 63] = Ows[(size_t)b * (NN * DD) + i];
        Wl[i >> 6][i & 63] = Wo[i];
    }
    __syncthreads();

    for (int i = tid; i < 64 * 64; i += 256) {
        int nn = i >> 6, d = i & 63;
        float acc = bo[d];
#pragma unroll 16
        for (int k = 0; k < 64; ++k) acc = fmaf(Ol[nn][k], Wl[d][k], acc);
        Cstar[(size_t)b * (NN * DD) + i] = acc;
    }
}

// ---------------------------------------------------------------------------
// Decoder init: h0/c0 = tanh(Cs @ W^T + b) per (n, b). One wave per (n,b).
// ---------------------------------------------------------------------------
__global__ __launch_bounds__(64)
void dec_init_kernel(const float* __restrict__ Cstar,
                     const float* __restrict__ WhI,
                     const float* __restrict__ bhI,
                     const float* __restrict__ WcI,
                     const float* __restrict__ bcI,
                     float* __restrict__ H0,
                     float* __restrict__ C0)
{
    const int n = blockIdx.x >> 5;
    const int b = blockIdx.x & 31;
    const int u = threadIdx.x;

    const float cs = Cstar[(size_t)b * (NN * DD) + (size_t)n * DD + u];
    const float4* Rh = reinterpret_cast<const float4*>(WhI + ((size_t)n * DD + u) * DD);
    const float4* Rc = reinterpret_cast<const float4*>(WcI + ((size_t)n * DD + u) * DD);
    float ah = bhI[n * DD + u];
    float ac = bcI[n * DD + u];
#pragma unroll
    for (int q = 0; q < 16; ++q) {
        const float4 wh = Rh[q], wc = Rc[q];
        float k0 = bcast(cs, 4 * q + 0);
        float k1 = bcast(cs, 4 * q + 1);
        float k2 = bcast(cs, 4 * q + 2);
        float k3 = bcast(cs, 4 * q + 3);
        ah = fmaf(wh.x, k0, ah); ah = fmaf(wh.y, k1, ah);
        ah = fmaf(wh.z, k2, ah); ah = fmaf(wh.w, k3, ah);
        ac = fmaf(wc.x, k0, ac); ac = fmaf(wc.y, k1, ac);
        ac = fmaf(wc.z, k2, ac); ac = fmaf(wc.w, k3, ac);
    }
    const size_t idx = ((size_t)n * BB + b) * DD + u;
    H0[idx] = tanhf_(ah);
    C0[idx] = tanhf_(ac);
}

// ---------------------------------------------------------------------------
// Decoder: block = (n, batch pair), 2 waves (k-halves); zero inputs;
// per-step y = h.ow + ob (wave w owns batch 2*bg+w).
// ---------------------------------------------------------------------------
__global__ __launch_bounds__(128, 2)
void dec_kernel(const float* __restrict__ Whh,
                const float* __restrict__ bias,
                const float* __restrict__ ow,
                const float* __restrict__ ob,
                const float* __restrict__ H0,
                const float* __restrict__ C0,
                float* __restrict__ recon,        // [B][L-1][N]
                float* __restrict__ pred)         // [B][N]
{
    const int n   = blockIdx.x >> 4;
    const int bg  = blockIdx.x & 15;
    const int tid = threadIdx.x;
    const int w   = tid >> 6;
    const int u   = tid & 63;
    const int kbase = w << 5;
    const int bb0 = 2 * bg, bb1 = 2 * bg + 1;
    const int bbm = 2 * bg + w;

    __shared__ float4 part[2][2][64];
    __shared__ float  hx[2][64];

    const float* Ri = Whh + (size_t)n * 16384 + (size_t)u * 64 + kbase;
    const float* Rf = Ri + 64 * 64;
    const float* Rg = Ri + 128 * 64;
    const float* Ro = Ri + 192 * 64;

    KLIST(DECLW)
    KLIST(LOADW)
    KLIST(PINW)

    const float* Bn = bias + n * 256;
    v2f bif = {Bn[u],       Bn[u +  64]};
    v2f bgo = {Bn[u + 128], Bn[u + 192]};
    pin(bif); pin(bgo);
    const float owu = ow[n * DD + u];
    const float obn = ob[n];

    float h0 = H0[((size_t)n * BB + bb0) * DD + u];
    float h1 = H0[((size_t)n * BB + bb1) * DD + u];
    float cm = C0[((size_t)n * BB + bbm) * DD + u];

#pragma unroll 1
    for (int t = 0; t < LL; ++t) {
        const v2f z = {0.0f, 0.0f};
        v2f aifA0 = (w == 0) ? bif : z;
        v2f agoA0 = (w == 0) ? bgo : z;
        v2f aifA1 = (w == 0) ? z : bif;
        v2f agoA1 = (w == 0) ? z : bgo;
        v2f aifB0 = z, agoB0 = z, aifB1 = z, agoB1 = z;

        KLIST(FMAK)

        const v2f aif0 = aifA0 + aifB0, ago0 = agoA0 + agoB0;
        const v2f aif1 = aifA1 + aifB1, ago1 = agoA1 + agoB1;

        part[w][0][u] = float4{aif0.x, aif0.y, ago0.x, ago0.y};
        part[w][1][u] = float4{aif1.x, aif1.y, ago1.x, ago1.y};
        __syncthreads();
        const float4 po = part[w ^ 1][w][u];
        const v2f mine_if = (w == 0) ? aif0 : aif1;
        const v2f mine_go = (w == 0) ? ago0 : ago1;
        const v2f gif = mine_if + v2f{po.x, po.y};
        const v2f ggo = mine_go + v2f{po.z, po.w};

        const float gi = sigmoidf_(gif.x), gf = sigmoidf_(gif.y);
        const float gg = tanhf_(ggo.x),    go = sigmoidf_(ggo.y);
        cm = gf * cm + gi * gg;
        const float hm = go * tanhf_(cm);

        float p = hm * owu;
#pragma unroll
        for (int off = 32; off >= 1; off >>= 1) p += __shfl_xor(p, off, 64);
        if (u == 0) {
            const float y = p + obn;
            if (t < LL - 1)
                recon[(size_t)bbm * ((LL - 1) * NN) + (size_t)t * NN + n] = y;
            else
                pred[(size_t)bbm * NN + n] = y;
        }

        hx[w][u] = hm;
        __syncthreads();
        const float ho = hx[w ^ 1][u];
        h0 = (w == 0) ? hm : ho;
        h1 = (w == 0) ? ho : hm;
    }
}

extern "C" void kernel_launch(void* const* d_in, const int* in_sizes, int n_in,
                              void* d_out, int out_size, void* d_ws, size_t ws_size,
                              hipStream_t stream) {
    (void)in_sizes; (void)n_in; (void)out_size; (void)ws_size;

    const float* X         = (const float*)d_in[0];
    const float* enc_Wih   = (const float*)d_in[1];
    const float* enc_Whh   = (const float*)d_in[2];
    const float* enc_b     = (const float*)d_in[3];
    const float* pool_w    = (const float*)d_in[4];
    const float* pool_b    = (const float*)d_in[5];
    const float* attn_Wqkv = (const float*)d_in[6];
    const float* attn_bqkv = (const float*)d_in[7];
    const float* attn_Wo   = (const float*)d_in[8];
    const float* attn_bo   = (const float*)d_in[9];
    // d_in[10] = dec_Wih: multiplied by all-zero inputs -> unused
    const float* dec_Whh   = (const float*)d_in[11];
    const float* dec_b     = (const float*)d_in[12];
    const float* init_h_W  = (const float*)d_in[13];
    const float* init_h_b  = (const float*)d_in[14];
    const float* init_c_W  = (const float*)d_in[15];
    const float* init_c_b  = (const float*)d_in[16];
    const float* out_w     = (const float*)d_in[17];
    const float* out_b     = (const float*)d_in[18];

    float* out   = (float*)d_out;
    float* recon = out;                                     // B*(L-1)*N
    float* pred  = out + (size_t)BB * (LL - 1) * NN;        // B*N
    float* cstar = pred + (size_t)BB * NN;                  // B*N*D

    float* Cws = (float*)d_ws;                              // [B][N][D]
    float* Ows = Cws + (size_t)BB * NN * DD;                // [B][N][D]
    // After proj, Cws/Ows are dead -> reuse for H0/C0 ([N][B][D] each)
    float* H0 = Cws;
    float* C0 = Ows;

    enc_kernel<<<dim3(NN * 16), dim3(128), 0, stream>>>(
        X, enc_Wih, enc_Whh, enc_b, pool_w, pool_b, Cws);

    attn_kernel<<<dim3(BB * HH), dim3(256), 0, stream>>>(
        Cws, attn_Wqkv, attn_bqkv, Ows);

    proj_kernel<<<dim3(BB), dim3(256), 0, stream>>>(
        Ows, attn_Wo, attn_bo, cstar);

    dec_init_kernel<<<dim3(NN * BB), dim3(64), 0, stream>>>(
        cstar, init_h_W, init_h_b, init_c_W, init_c_b, H0, C0);

    dec_kernel<<<dim3(NN * 16), dim3(128), 0, stream>>>(
        dec_Whh, dec_b, out_w, out_b, H0, C0, recon, pred);
}